// Round 14
// baseline (282.643 us; speedup 1.0000x reference)
//
#include <hip/hip_runtime.h>

#define DI __device__ __forceinline__

typedef __attribute__((ext_vector_type(8))) short bf16x8;
typedef __attribute__((ext_vector_type(4))) float f32x4;
typedef __attribute__((ext_vector_type(16))) float f32x16;
typedef __attribute__((ext_vector_type(4))) unsigned u32x4;
typedef __attribute__((ext_vector_type(2))) unsigned u32x2;

static constexpr int B_ = 4, L_ = 2048, D_ = 1024, H_ = 16, DV_ = 64;
static constexpr int M_ = B_ * L_;  // 8192
static constexpr float SCALE_LOG2 = 0.18033688011112042f;  // (1/sqrt(64)) * log2(e)

DI short f2b(float f) {
  union { float f; unsigned u; } v; v.f = f;
  unsigned r = v.u + 0x7FFFu + ((v.u >> 16) & 1u);
  return (short)(r >> 16);
}

DI float b2f(short s) {
  union { unsigned u; float f; } v;
  v.u = ((unsigned)(unsigned short)s) << 16;
  return v.f;
}

DI unsigned cvtpk(float lo, float hi) {  // u32 = [bf16(lo) | bf16(hi)<<16]
  unsigned r;
  asm("v_cvt_pk_bf16_f32 %0, %1, %2" : "=v"(r) : "v"(lo), "v"(hi));
  return r;
}

DI void gl_lds16(const void* g, void* l) {
  __builtin_amdgcn_global_load_lds(
      (const __attribute__((address_space(1))) unsigned int*)g,
      (__attribute__((address_space(3))) unsigned int*)l, 16, 0, 0);
}

#define MFMA16(a, b, c) __builtin_amdgcn_mfma_f32_16x16x32_bf16((a), (b), (c), 0, 0, 0)
#define MFMA32(a, b, c) __builtin_amdgcn_mfma_f32_32x32x16_bf16((a), (b), (c), 0, 0, 0)

// ---------------------------------------------------------------- weights f32 -> bf16 (one dispatch, blockIdx.y selects)
__global__ __launch_bounds__(256) void cvtw_kernel(const float* __restrict__ W0,
                                                   const float* __restrict__ W1,
                                                   const float* __restrict__ W2,
                                                   const float* __restrict__ W3,
                                                   short* __restrict__ dst) {
  const int p = blockIdx.y;
  const float* s = p == 0 ? W0 : p == 1 ? W1 : p == 2 ? W2 : W3;
  short* d = dst + (size_t)p * 1048576;
  int i0 = (blockIdx.x * 256 + threadIdx.x) * 8;
  int stride = gridDim.x * 256 * 8;
  for (int i = i0; i < 1048576; i += stride) {
    float4 a = *(const float4*)(s + i);
    float4 b = *(const float4*)(s + i + 4);
    u32x4 o;
    o[0] = cvtpk(a.x, a.y);
    o[1] = cvtpk(a.z, a.w);
    o[2] = cvtpk(b.x, b.y);
    o[3] = cvtpk(b.z, b.w);
    *(u32x4*)(d + i) = o;
  }
}

// ---------------------------------------------------------------- fused QKV projection GEMM (f32 A, LDS-staged)
// 128x256 tile (r11-proven loop): A staged ONCE per K-step, reused for TWO 128-wide
// B panels -> A L3 re-read traffic halves (the measured qkvf replay bottleneck).
// Epilogue: r10-proven row-major writes for ALL p (no scatter; r11's regression was
// solely its transposed-V scatter write, WRITE_SIZE 353MB).
__global__ __launch_bounds__(256, 3) void gemm_qkvf(const float* __restrict__ Xq,
                                                    const float* __restrict__ Xk,
                                                    const float* __restrict__ Xv,
                                                    const short* __restrict__ Wall,
                                                    const float* __restrict__ bq,
                                                    const float* __restrict__ bk,
                                                    const float* __restrict__ bv,
                                                    short* __restrict__ Hq,
                                                    short* __restrict__ Hk,
                                                    short* __restrict__ Hv) {
  constexpr int K = 1024, N = 1024;
  __shared__ __align__(16) float Asf[128 * 32];
  __shared__ __align__(16) short Bs[2][128 * 32];
  const int p = blockIdx.y;
  const float* A = p == 0 ? Xq : p == 1 ? Xk : Xv;
  const short* Wt = Wall + (size_t)p * 1048576;
  const float* bias = p == 0 ? bq : p == 1 ? bk : bv;
  short* outb = p == 0 ? Hq : p == 1 ? Hk : Hv;

  const int tid = threadIdx.x;
  const int w = tid >> 6, lane = tid & 63;
  const int c = lane & 15, g = lane >> 4;
  const int bid = (blockIdx.x & 7) * 32 + (blockIdx.x >> 3);  // XCD swizzle (256 = 8*32)
  const int bn = bid & 3, bm = bid >> 2;
  const int wr = w >> 1, wc = w & 1;

  f32x4 acc0[4][4] = {};
  f32x4 acc1[4][4] = {};

  for (int kt = 0; kt < K / 32; ++kt) {
    __syncthreads();
    // A: f32, 1024 chunks of 16B, source pre-swizzled (rule #21)
#pragma unroll
    for (int it = 0; it < 4; ++it) {
      int slot = it * 256 + tid;
      int row = slot >> 3, ch = (slot & 7) ^ (row & 7);
      gl_lds16(A + ((size_t)(bm * 128 + row) * K + kt * 32 + ch * 4),
               &Asf[(it * 256 + w * 64) * 4]);
    }
    // W: bf16, two 128-row panels, linear dest (proven staging)
#pragma unroll
    for (int bn2 = 0; bn2 < 2; ++bn2)
#pragma unroll
      for (int ia = 0; ia < 2; ++ia) {
        int slot = ia * 256 + tid;
        int row = slot >> 2, ch = slot & 3;
        gl_lds16(Wt + ((size_t)(bn * 256 + bn2 * 128 + row) * K + kt * 32 + ch * 8),
                 &Bs[bn2][(ia * 256 + w * 64) * 8]);
      }
    __syncthreads();
    bf16x8 af[4], bf0[4], bf1[4];
#pragma unroll
    for (int mi = 0; mi < 4; ++mi) {
      int r = wr * 64 + mi * 16 + c;
      int c0 = (((2 * g) ^ (r & 7)) * 4);
      int c1 = (((2 * g + 1) ^ (r & 7)) * 4);
      float4 lo = *(const float4*)&Asf[r * 32 + c0];
      float4 hi = *(const float4*)&Asf[r * 32 + c1];
      u32x4 pk;
      pk[0] = cvtpk(lo.x, lo.y);
      pk[1] = cvtpk(lo.z, lo.w);
      pk[2] = cvtpk(hi.x, hi.y);
      pk[3] = cvtpk(hi.z, hi.w);
      af[mi] = __builtin_bit_cast(bf16x8, pk);
    }
#pragma unroll
    for (int ni = 0; ni < 4; ++ni) {
      bf0[ni] = *(const bf16x8*)&Bs[0][(wc * 64 + ni * 16 + c) * 32 + g * 8];
      bf1[ni] = *(const bf16x8*)&Bs[1][(wc * 64 + ni * 16 + c) * 32 + g * 8];
    }
#pragma unroll
    for (int mi = 0; mi < 4; ++mi)
#pragma unroll
      for (int ni = 0; ni < 4; ++ni) {
        acc0[mi][ni] = MFMA16(af[mi], bf0[ni], acc0[mi][ni]);
        acc1[mi][ni] = MFMA16(af[mi], bf1[ni], acc1[mi][ni]);
      }
  }

#pragma unroll
  for (int bn2 = 0; bn2 < 2; ++bn2) {
    float bvv[4];
#pragma unroll
    for (int ni = 0; ni < 4; ++ni)
      bvv[ni] = bias[bn * 256 + bn2 * 128 + wc * 64 + ni * 16 + c];
#pragma unroll
    for (int mi = 0; mi < 4; ++mi)
#pragma unroll
      for (int ni = 0; ni < 4; ++ni)
#pragma unroll
        for (int j = 0; j < 4; ++j) {
          int row = bm * 128 + wr * 64 + mi * 16 + g * 4 + j;
          int col = bn * 256 + bn2 * 128 + wc * 64 + ni * 16 + c;
          f32x4 a = bn2 ? acc1[mi][ni] : acc0[mi][ni];
          outb[(size_t)row * N + col] = f2b(a[j] + bvv[ni]);
        }
  }
}

// ---------------------------------------------------------------- GEMM (bf16 A): final projection (proven)
template <int OUTF32>
__global__ __launch_bounds__(256) void gemm_bt(const short* __restrict__ A,
                                               const short* __restrict__ Wt,
                                               const float* __restrict__ bias,
                                               float* __restrict__ outf,
                                               short* __restrict__ outb) {
  constexpr int K = 1024, N = 1024;
  __shared__ __align__(16) short As[128 * 32];
  __shared__ __align__(16) short Bs[128 * 32];
  const int tid = threadIdx.x;
  const int w = tid >> 6, lane = tid & 63;
  const int c = lane & 15, g = lane >> 4;
  const int bid = (blockIdx.x & 7) * 64 + (blockIdx.x >> 3);  // XCD swizzle (512 = 8*64)
  const int bn = bid & 7, bm = bid >> 3;
  const int wr = w >> 1, wc = w & 1;

  f32x4 acc[4][4] = {};

  for (int kt = 0; kt < K / 32; ++kt) {
    __syncthreads();
#pragma unroll
    for (int ia = 0; ia < 2; ++ia) {
      int slot = ia * 256 + tid;
      int row = slot >> 2, ch = slot & 3;
      gl_lds16(A + ((size_t)(bm * 128 + row) * K + kt * 32 + ch * 8),
               &As[(ia * 256 + w * 64) * 8]);
      gl_lds16(Wt + ((size_t)(bn * 128 + row) * K + kt * 32 + ch * 8),
               &Bs[(ia * 256 + w * 64) * 8]);
    }
    __syncthreads();
    bf16x8 af[4], bf[4];
#pragma unroll
    for (int mi = 0; mi < 4; ++mi)
      af[mi] = *(const bf16x8*)&As[(wr * 64 + mi * 16 + c) * 32 + g * 8];
#pragma unroll
    for (int ni = 0; ni < 4; ++ni)
      bf[ni] = *(const bf16x8*)&Bs[(wc * 64 + ni * 16 + c) * 32 + g * 8];
#pragma unroll
    for (int mi = 0; mi < 4; ++mi)
#pragma unroll
      for (int ni = 0; ni < 4; ++ni)
        acc[mi][ni] = MFMA16(af[mi], bf[ni], acc[mi][ni]);
  }

  float bv[4];
#pragma unroll
  for (int ni = 0; ni < 4; ++ni) bv[ni] = bias[bn * 128 + wc * 64 + ni * 16 + c];
#pragma unroll
  for (int mi = 0; mi < 4; ++mi)
#pragma unroll
    for (int ni = 0; ni < 4; ++ni)
#pragma unroll
      for (int j = 0; j < 4; ++j) {
        int row = bm * 128 + wr * 64 + mi * 16 + g * 4 + j;
        int col = bn * 128 + wc * 64 + ni * 16 + c;
        float v = acc[mi][ni][j] + bv[ni];
        if (OUTF32)
          outf[(size_t)row * N + col] = v;
        else
          outb[(size_t)row * N + col] = f2b(v);
      }
}

// ---------------------------------------------------------------- Hv [B,L,D] -> Hvt [B,H,DV,L] (proven)
__global__ __launch_bounds__(256) void transpose_kernel(const short* __restrict__ Hv,
                                                        short* __restrict__ Hvt) {
  __shared__ short T[64 * 72];
  int bid = blockIdx.x;
  const int lt = bid & 31;
  const int h = (bid >> 5) & 15;
  const int b = bid >> 9;
  const int l0 = lt * 64;
  const int tid = threadIdx.x;
#pragma unroll
  for (int it = 0; it < 2; ++it) {
    int slot = it * 256 + tid;
    int r = slot >> 3, ch = slot & 7;
    bf16x8 v = *(const bf16x8*)&Hv[(size_t)(b * L_ + l0 + r) * D_ + h * DV_ + ch * 8];
    *(bf16x8*)&T[r * 72 + ch * 8] = v;
  }
  __syncthreads();
#pragma unroll
  for (int it = 0; it < 2; ++it) {
    int slot = it * 256 + tid;
    int dv = slot >> 3, ch = slot & 7;
    bf16x8 o;
#pragma unroll
    for (int i = 0; i < 8; ++i) o[i] = T[(ch * 8 + i) * 72 + dv];
    *(bf16x8*)&Hvt[(size_t)((b * H_ + h) * DV_ + dv) * L_ + l0 + ch * 8] = o;
  }
}

// ---------------------------------------------------------------- flash attention v6 (r10-verified, unchanged)
__global__ __launch_bounds__(256, 2) void attn_kernel(const short* __restrict__ Hq,
                                                      const short* __restrict__ Hk,
                                                      const short* __restrict__ Hvt,
                                                      short* __restrict__ Aout) {
  __shared__ __align__(16) short lds[34816];
  const int tid = threadIdx.x;  // 0..255
  const int w = tid >> 6, lane = tid & 63;
  const int c31 = lane & 31, g1 = lane >> 5;
  const int sw = (blockIdx.x & 7) * 64 + (blockIdx.x >> 3);  // XCD swizzle (512 = 8*64)
  const int qb = sw & 7;
  const int h = (sw >> 3) & 15;
  const int b = sw >> 7;
  const int q0 = qb * 256;

  bf16x8 qf0[4], qf1[4];
#pragma unroll
  for (int hh = 0; hh < 2; ++hh) {
    const short* qptr =
        Hq + (size_t)(b * L_ + q0 + w * 64 + hh * 32 + c31) * D_ + h * 64 + g1 * 8;
#pragma unroll
    for (int ks = 0; ks < 4; ++ks) {
      bf16x8 raw = *(const bf16x8*)(qptr + ks * 16);
      u32x4 pk;
#pragma unroll
      for (int i = 0; i < 4; ++i)
        pk[i] = cvtpk(b2f(raw[2 * i]) * SCALE_LOG2, b2f(raw[2 * i + 1]) * SCALE_LOG2);
      if (hh == 0) qf0[ks] = __builtin_bit_cast(bf16x8, pk);
      else         qf1[ks] = __builtin_bit_cast(bf16x8, pk);
    }
  }

  f32x16 O00 = {}, O01 = {}, O10 = {}, O11 = {};
  float ls0 = 0.f, ls1 = 0.f;
  unsigned* Pw0 = (unsigned*)(lds + 16384) + (w * 2 + 0) * 1152;  // [32 q][36 u32]
  unsigned* Pw1 = (unsigned*)(lds + 16384) + (w * 2 + 1) * 1152;

  auto stage = [&](int buf, int kv0) {
    short* Kb = lds + buf * 8192;
    short* Vb = Kb + 4096;
#pragma unroll
    for (int it = 0; it < 2; ++it) {
      int slot = it * 256 + tid;
      int row = slot >> 3;
      int ch = (slot & 7) ^ (row & 7);  // pre-swizzled source chunk (rule #21)
      gl_lds16(Hk + (size_t)(b * L_ + kv0 + row) * D_ + h * 64 + ch * 8,
               Kb + (it * 256 + w * 64) * 8);
      gl_lds16(Hvt + (size_t)((b * H_ + h) * DV_ + row) * L_ + kv0 + ch * 8,
               Vb + (it * 256 + w * 64) * 8);
    }
  };

  stage(0, 0);
  int cur = 0;
  for (int t = 0; t < L_ / 64; ++t) {
    __syncthreads();  // vmcnt drained: buf[cur] ready
    if (t + 1 < L_ / 64) stage(cur ^ 1, (t + 1) * 64);  // prefetch under compute
    const short* Kb = lds + cur * 8192;
    const short* Vb = Kb + 4096;

    f32x16 sA0 = {}, sB0 = {}, sA1 = {}, sB1 = {};
    __builtin_amdgcn_s_setprio(1);
#pragma unroll
    for (int ks = 0; ks < 4; ++ks) {
      int cp = (((2 * ks + g1) ^ (c31 & 7)) * 8);
      bf16x8 k0 = *(const bf16x8*)(Kb + c31 * 64 + cp);
      bf16x8 k1 = *(const bf16x8*)(Kb + (32 + c31) * 64 + cp);
      sA0 = MFMA32(k0, qf0[ks], sA0);
      sB0 = MFMA32(k1, qf0[ks], sB0);
      sA1 = MFMA32(k0, qf1[ks], sA1);
      sB1 = MFMA32(k1, qf1[ks], sB1);
    }
    __builtin_amdgcn_s_setprio(0);

    {
      float rs = 0.f;
#pragma unroll
      for (int p = 0; p < 4; ++p) {
        float a0 = __builtin_amdgcn_exp2f(sA0[4 * p]);
        float a1 = __builtin_amdgcn_exp2f(sA0[4 * p + 1]);
        float a2 = __builtin_amdgcn_exp2f(sA0[4 * p + 2]);
        float a3 = __builtin_amdgcn_exp2f(sA0[4 * p + 3]);
        float b0 = __builtin_amdgcn_exp2f(sB0[4 * p]);
        float b1 = __builtin_amdgcn_exp2f(sB0[4 * p + 1]);
        float b2 = __builtin_amdgcn_exp2f(sB0[4 * p + 2]);
        float b3 = __builtin_amdgcn_exp2f(sB0[4 * p + 3]);
        rs += (a0 + a1) + (a2 + a3) + (b0 + b1) + (b2 + b3);
        u32x2 lo, hi;
        lo[0] = cvtpk(a0, a1);
        lo[1] = cvtpk(a2, a3);
        hi[0] = cvtpk(b0, b1);
        hi[1] = cvtpk(b2, b3);
        *(u32x2*)(Pw0 + c31 * 36 + 4 * p + 2 * g1) = lo;
        *(u32x2*)(Pw0 + c31 * 36 + 16 + 4 * p + 2 * g1) = hi;
      }
      ls0 += rs + __shfl_xor(rs, 32);
    }
    {
      float rs = 0.f;
#pragma unroll
      for (int p = 0; p < 4; ++p) {
        float a0 = __builtin_amdgcn_exp2f(sA1[4 * p]);
        float a1 = __builtin_amdgcn_exp2f(sA1[4 * p + 1]);
        float a2 = __builtin_amdgcn_exp2f(sA1[4 * p + 2]);
        float a3 = __builtin_amdgcn_exp2f(sA1[4 * p + 3]);
        float b0 = __builtin_amdgcn_exp2f(sB1[4 * p]);
        float b1 = __builtin_amdgcn_exp2f(sB1[4 * p + 1]);
        float b2 = __builtin_amdgcn_exp2f(sB1[4 * p + 2]);
        float b3 = __builtin_amdgcn_exp2f(sB1[4 * p + 3]);
        rs += (a0 + a1) + (a2 + a3) + (b0 + b1) + (b2 + b3);
        u32x2 lo, hi;
        lo[0] = cvtpk(a0, a1);
        lo[1] = cvtpk(a2, a3);
        hi[0] = cvtpk(b0, b1);
        hi[1] = cvtpk(b2, b3);
        *(u32x2*)(Pw1 + c31 * 36 + 4 * p + 2 * g1) = lo;
        *(u32x2*)(Pw1 + c31 * 36 + 16 + 4 * p + 2 * g1) = hi;
      }
      ls1 += rs + __shfl_xor(rs, 32);
    }

    __builtin_amdgcn_s_setprio(1);
#pragma unroll
    for (int ks2 = 0; ks2 < 4; ++ks2) {
      int cp = (((2 * ks2 + g1) ^ (c31 & 7)) * 8);
      bf16x8 vf0 = *(const bf16x8*)(Vb + c31 * 64 + cp);
      bf16x8 vf1 = *(const bf16x8*)(Vb + (32 + c31) * 64 + cp);
      u32x4 pk0 = *(const u32x4*)(Pw0 + c31 * 36 + ks2 * 8 + g1 * 4);
      bf16x8 pf0 = __builtin_bit_cast(bf16x8, pk0);
      O00 = MFMA32(vf0, pf0, O00);
      O01 = MFMA32(vf1, pf0, O01);
      u32x4 pk1 = *(const u32x4*)(Pw1 + c31 * 36 + ks2 * 8 + g1 * 4);
      bf16x8 pf1 = __builtin_bit_cast(bf16x8, pk1);
      O10 = MFMA32(vf0, pf1, O10);
      O11 = MFMA32(vf1, pf1, O11);
    }
    __builtin_amdgcn_s_setprio(0);
    cur ^= 1;
  }

  float inv0 = 1.0f / ls0;
  float inv1 = 1.0f / ls1;
  __syncthreads();
  short* Os = lds;
#define EPI(OA, OB, INV, HH)                                        \
  {                                                                 \
    _Pragma("unroll") for (int dt = 0; dt < 2; ++dt) {              \
      _Pragma("unroll") for (int rq = 0; rq < 4; ++rq) {            \
        float e0 = (dt ? OB[4 * rq] : OA[4 * rq]) * INV;            \
        float e1 = (dt ? OB[4 * rq + 1] : OA[4 * rq + 1]) * INV;    \
        float e2 = (dt ? OB[4 * rq + 2] : OA[4 * rq + 2]) * INV;    \
        float e3 = (dt ? OB[4 * rq + 3] : OA[4 * rq + 3]) * INV;    \
        u32x2 pr;                                                   \
        pr[0] = cvtpk(e0, e1);                                      \
        pr[1] = cvtpk(e2, e3);                                      \
        int q = w * 64 + (HH)*32 + c31;                             \
        int dv = dt * 32 + 8 * rq + 4 * g1;                         \
        *(u32x2*)&Os[q * 72 + dv] = pr;                             \
      }                                                             \
    }                                                               \
  }
  EPI(O00, O01, inv0, 0)
  EPI(O10, O11, inv1, 1)
#undef EPI
  __syncthreads();
#pragma unroll
  for (int it = 0; it < 2; ++it) {
    const int r = it * 128 + (tid >> 1), hf = tid & 1;
    const size_t obase = (size_t)(b * L_ + q0 + r) * D_ + h * 64 + hf * 32;
#pragma unroll
    for (int cc = 0; cc < 4; ++cc) {
      bf16x8 vv = *(const bf16x8*)&Os[r * 72 + hf * 32 + cc * 8];
      *(bf16x8*)&Aout[obase + cc * 8] = vv;
    }
  }
}

// ---------------------------------------------------------------- host
extern "C" void kernel_launch(void* const* d_in, const int* in_sizes, int n_in,
                              void* d_out, int out_size, void* d_ws, size_t ws_size,
                              hipStream_t stream) {
  (void)in_sizes; (void)n_in; (void)out_size; (void)ws_size;
  const float* q = (const float*)d_in[0];
  const float* k = (const float*)d_in[1];
  const float* v = (const float*)d_in[2];
  const float* Wq = (const float*)d_in[3];
  const float* bq = (const float*)d_in[4];
  const float* Wk = (const float*)d_in[5];
  const float* bk = (const float*)d_in[6];
  const float* Wv = (const float*)d_in[7];
  const float* bv = (const float*)d_in[8];
  const float* Wc = (const float*)d_in[9];
  const float* bc = (const float*)d_in[10];
  float* out = (float*)d_out;

  short* ws = (short*)d_ws;
  const size_t SZ = (size_t)M_ * D_;   // 8388608
  const size_t WSZ = (size_t)D_ * D_;  // 1048576
  short* wqb = ws;                      // 4 contiguous weight slots (wq,wk,wv,wc)
  short* wcb = ws + 3 * WSZ;
  short* hq = ws + 4 * WSZ;
  short* hk = hq + SZ;
  short* hv = hk + SZ;
  short* hvt = hv + SZ;
  short* aout = hv;  // hv slot free after transpose

  // all weights -> bf16 (one dispatch)
  dim3 gw(128, 4);
  cvtw_kernel<<<gw, 256, 0, stream>>>(Wq, Wk, Wv, Wc, wqb);

  // fused QKV projections: 128x256 tile, A staged once per K-step (2-panel reuse)
  dim3 gq(256, 3);
  gemm_qkvf<<<gq, 256, 0, stream>>>(q, k, v, wqb, bq, bk, bv, hq, hk, hv);

  // V transpose for attention A-operand
  transpose_kernel<<<2048, 256, 0, stream>>>(hv, hvt);

  // attention (512 blocks x 256 threads, 4 waves x 64 q, 2 blocks/CU)
  attn_kernel<<<512, 256, 0, stream>>>(hq, hk, hvt, aout);

  // output projection (f32 out + bias)
  gemm_bt<1><<<512, 256, 0, stream>>>(aout, wcb, bc, out, nullptr);
}

// Round 15
// 253.706 us; speedup vs baseline: 1.1141x; 1.1141x over previous
//
#include <hip/hip_runtime.h>

#define DI __device__ __forceinline__

typedef __attribute__((ext_vector_type(8))) short bf16x8;
typedef __attribute__((ext_vector_type(4))) float f32x4;
typedef __attribute__((ext_vector_type(16))) float f32x16;
typedef __attribute__((ext_vector_type(4))) unsigned u32x4;
typedef __attribute__((ext_vector_type(2))) unsigned u32x2;

static constexpr int B_ = 4, L_ = 2048, D_ = 1024, H_ = 16, DV_ = 64;
static constexpr int M_ = B_ * L_;  // 8192
static constexpr float SCALE_LOG2 = 0.18033688011112042f;  // (1/sqrt(64)) * log2(e)

DI short f2b(float f) {
  union { float f; unsigned u; } v; v.f = f;
  unsigned r = v.u + 0x7FFFu + ((v.u >> 16) & 1u);
  return (short)(r >> 16);
}

DI float b2f(short s) {
  union { unsigned u; float f; } v;
  v.u = ((unsigned)(unsigned short)s) << 16;
  return v.f;
}

DI unsigned cvtpk(float lo, float hi) {  // u32 = [bf16(lo) | bf16(hi)<<16]
  unsigned r;
  asm("v_cvt_pk_bf16_f32 %0, %1, %2" : "=v"(r) : "v"(lo), "v"(hi));
  return r;
}

DI void gl_lds16(const void* g, void* l) {
  __builtin_amdgcn_global_load_lds(
      (const __attribute__((address_space(1))) unsigned int*)g,
      (__attribute__((address_space(3))) unsigned int*)l, 16, 0, 0);
}

#define MFMA16(a, b, c) __builtin_amdgcn_mfma_f32_16x16x32_bf16((a), (b), (c), 0, 0, 0)
#define MFMA32(a, b, c) __builtin_amdgcn_mfma_f32_32x32x16_bf16((a), (b), (c), 0, 0, 0)

// ---------------------------------------------------------------- weights f32 -> bf16 (one dispatch, blockIdx.y selects)
__global__ __launch_bounds__(256) void cvtw_kernel(const float* __restrict__ W0,
                                                   const float* __restrict__ W1,
                                                   const float* __restrict__ W2,
                                                   const float* __restrict__ W3,
                                                   short* __restrict__ dst) {
  const int p = blockIdx.y;
  const float* s = p == 0 ? W0 : p == 1 ? W1 : p == 2 ? W2 : W3;
  short* d = dst + (size_t)p * 1048576;
  int i0 = (blockIdx.x * 256 + threadIdx.x) * 8;
  int stride = gridDim.x * 256 * 8;
  for (int i = i0; i < 1048576; i += stride) {
    float4 a = *(const float4*)(s + i);
    float4 b = *(const float4*)(s + i + 4);
    u32x4 o;
    o[0] = cvtpk(a.x, a.y);
    o[1] = cvtpk(a.z, a.w);
    o[2] = cvtpk(b.x, b.y);
    o[3] = cvtpk(b.z, b.w);
    *(u32x4*)(d + i) = o;
  }
}

// ---------------------------------------------------------------- fused QKV projection GEMM (f32 A, LDS-staged)
// 128x256 tile: A staged ONCE per K-step, reused for TWO B panels; 32 MFMA per barrier
// pair (vs 16). NO min-waves launch bound: the 2-panel live set (~200 VGPR) must not be
// capped — r11/r14's (256,3) cap forced acc spills (VGPR 84, WRITE_SIZE 331-353 MB).
__global__ __launch_bounds__(256) void gemm_qkvf(const float* __restrict__ Xq,
                                                 const float* __restrict__ Xk,
                                                 const float* __restrict__ Xv,
                                                 const short* __restrict__ Wall,
                                                 const float* __restrict__ bq,
                                                 const float* __restrict__ bk,
                                                 const float* __restrict__ bv,
                                                 short* __restrict__ Hq,
                                                 short* __restrict__ Hk,
                                                 short* __restrict__ Hv) {
  constexpr int K = 1024, N = 1024;
  __shared__ __align__(16) float Asf[128 * 32];
  __shared__ __align__(16) short Bs[2][128 * 32];
  const int p = blockIdx.y;
  const float* A = p == 0 ? Xq : p == 1 ? Xk : Xv;
  const short* Wt = Wall + (size_t)p * 1048576;
  const float* bias = p == 0 ? bq : p == 1 ? bk : bv;
  short* outb = p == 0 ? Hq : p == 1 ? Hk : Hv;

  const int tid = threadIdx.x;
  const int w = tid >> 6, lane = tid & 63;
  const int c = lane & 15, g = lane >> 4;
  const int bid = (blockIdx.x & 7) * 32 + (blockIdx.x >> 3);  // XCD swizzle (256 = 8*32)
  const int bn = bid & 3, bm = bid >> 2;
  const int wr = w >> 1, wc = w & 1;

  f32x4 acc0[4][4] = {};
  f32x4 acc1[4][4] = {};

  for (int kt = 0; kt < K / 32; ++kt) {
    __syncthreads();
    // A: f32, 1024 chunks of 16B, source pre-swizzled (rule #21)
#pragma unroll
    for (int it = 0; it < 4; ++it) {
      int slot = it * 256 + tid;
      int row = slot >> 3, ch = (slot & 7) ^ (row & 7);
      gl_lds16(A + ((size_t)(bm * 128 + row) * K + kt * 32 + ch * 4),
               &Asf[(it * 256 + w * 64) * 4]);
    }
    // W: bf16, two 128-row panels, linear dest (proven staging)
#pragma unroll
    for (int bn2 = 0; bn2 < 2; ++bn2)
#pragma unroll
      for (int ia = 0; ia < 2; ++ia) {
        int slot = ia * 256 + tid;
        int row = slot >> 2, ch = slot & 3;
        gl_lds16(Wt + ((size_t)(bn * 256 + bn2 * 128 + row) * K + kt * 32 + ch * 8),
                 &Bs[bn2][(ia * 256 + w * 64) * 8]);
      }
    __syncthreads();
    bf16x8 af[4], bf0[4], bf1[4];
#pragma unroll
    for (int mi = 0; mi < 4; ++mi) {
      int r = wr * 64 + mi * 16 + c;
      int c0 = (((2 * g) ^ (r & 7)) * 4);
      int c1 = (((2 * g + 1) ^ (r & 7)) * 4);
      float4 lo = *(const float4*)&Asf[r * 32 + c0];
      float4 hi = *(const float4*)&Asf[r * 32 + c1];
      u32x4 pk;
      pk[0] = cvtpk(lo.x, lo.y);
      pk[1] = cvtpk(lo.z, lo.w);
      pk[2] = cvtpk(hi.x, hi.y);
      pk[3] = cvtpk(hi.z, hi.w);
      af[mi] = __builtin_bit_cast(bf16x8, pk);
    }
#pragma unroll
    for (int ni = 0; ni < 4; ++ni) {
      bf0[ni] = *(const bf16x8*)&Bs[0][(wc * 64 + ni * 16 + c) * 32 + g * 8];
      bf1[ni] = *(const bf16x8*)&Bs[1][(wc * 64 + ni * 16 + c) * 32 + g * 8];
    }
#pragma unroll
    for (int mi = 0; mi < 4; ++mi)
#pragma unroll
      for (int ni = 0; ni < 4; ++ni) {
        acc0[mi][ni] = MFMA16(af[mi], bf0[ni], acc0[mi][ni]);
        acc1[mi][ni] = MFMA16(af[mi], bf1[ni], acc1[mi][ni]);
      }
  }

#pragma unroll
  for (int bn2 = 0; bn2 < 2; ++bn2) {
    float bvv[4];
#pragma unroll
    for (int ni = 0; ni < 4; ++ni)
      bvv[ni] = bias[bn * 256 + bn2 * 128 + wc * 64 + ni * 16 + c];
#pragma unroll
    for (int mi = 0; mi < 4; ++mi)
#pragma unroll
      for (int ni = 0; ni < 4; ++ni)
#pragma unroll
        for (int j = 0; j < 4; ++j) {
          int row = bm * 128 + wr * 64 + mi * 16 + g * 4 + j;
          int col = bn * 256 + bn2 * 128 + wc * 64 + ni * 16 + c;
          f32x4 a = bn2 ? acc1[mi][ni] : acc0[mi][ni];
          outb[(size_t)row * N + col] = f2b(a[j] + bvv[ni]);
        }
  }
}

// ---------------------------------------------------------------- GEMM (bf16 A): final projection (proven)
template <int OUTF32>
__global__ __launch_bounds__(256) void gemm_bt(const short* __restrict__ A,
                                               const short* __restrict__ Wt,
                                               const float* __restrict__ bias,
                                               float* __restrict__ outf,
                                               short* __restrict__ outb) {
  constexpr int K = 1024, N = 1024;
  __shared__ __align__(16) short As[128 * 32];
  __shared__ __align__(16) short Bs[128 * 32];
  const int tid = threadIdx.x;
  const int w = tid >> 6, lane = tid & 63;
  const int c = lane & 15, g = lane >> 4;
  const int bid = (blockIdx.x & 7) * 64 + (blockIdx.x >> 3);  // XCD swizzle (512 = 8*64)
  const int bn = bid & 7, bm = bid >> 3;
  const int wr = w >> 1, wc = w & 1;

  f32x4 acc[4][4] = {};

  for (int kt = 0; kt < K / 32; ++kt) {
    __syncthreads();
#pragma unroll
    for (int ia = 0; ia < 2; ++ia) {
      int slot = ia * 256 + tid;
      int row = slot >> 2, ch = slot & 3;
      gl_lds16(A + ((size_t)(bm * 128 + row) * K + kt * 32 + ch * 8),
               &As[(ia * 256 + w * 64) * 8]);
      gl_lds16(Wt + ((size_t)(bn * 128 + row) * K + kt * 32 + ch * 8),
               &Bs[(ia * 256 + w * 64) * 8]);
    }
    __syncthreads();
    bf16x8 af[4], bf[4];
#pragma unroll
    for (int mi = 0; mi < 4; ++mi)
      af[mi] = *(const bf16x8*)&As[(wr * 64 + mi * 16 + c) * 32 + g * 8];
#pragma unroll
    for (int ni = 0; ni < 4; ++ni)
      bf[ni] = *(const bf16x8*)&Bs[(wc * 64 + ni * 16 + c) * 32 + g * 8];
#pragma unroll
    for (int mi = 0; mi < 4; ++mi)
#pragma unroll
      for (int ni = 0; ni < 4; ++ni)
        acc[mi][ni] = MFMA16(af[mi], bf[ni], acc[mi][ni]);
  }

  float bv[4];
#pragma unroll
  for (int ni = 0; ni < 4; ++ni) bv[ni] = bias[bn * 128 + wc * 64 + ni * 16 + c];
#pragma unroll
  for (int mi = 0; mi < 4; ++mi)
#pragma unroll
    for (int ni = 0; ni < 4; ++ni)
#pragma unroll
      for (int j = 0; j < 4; ++j) {
        int row = bm * 128 + wr * 64 + mi * 16 + g * 4 + j;
        int col = bn * 128 + wc * 64 + ni * 16 + c;
        float v = acc[mi][ni][j] + bv[ni];
        if (OUTF32)
          outf[(size_t)row * N + col] = v;
        else
          outb[(size_t)row * N + col] = f2b(v);
      }
}

// ---------------------------------------------------------------- Hv [B,L,D] -> Hvt [B,H,DV,L] (proven)
__global__ __launch_bounds__(256) void transpose_kernel(const short* __restrict__ Hv,
                                                        short* __restrict__ Hvt) {
  __shared__ short T[64 * 72];
  int bid = blockIdx.x;
  const int lt = bid & 31;
  const int h = (bid >> 5) & 15;
  const int b = bid >> 9;
  const int l0 = lt * 64;
  const int tid = threadIdx.x;
#pragma unroll
  for (int it = 0; it < 2; ++it) {
    int slot = it * 256 + tid;
    int r = slot >> 3, ch = slot & 7;
    bf16x8 v = *(const bf16x8*)&Hv[(size_t)(b * L_ + l0 + r) * D_ + h * DV_ + ch * 8];
    *(bf16x8*)&T[r * 72 + ch * 8] = v;
  }
  __syncthreads();
#pragma unroll
  for (int it = 0; it < 2; ++it) {
    int slot = it * 256 + tid;
    int dv = slot >> 3, ch = slot & 7;
    bf16x8 o;
#pragma unroll
    for (int i = 0; i < 8; ++i) o[i] = T[(ch * 8 + i) * 72 + dv];
    *(bf16x8*)&Hvt[(size_t)((b * H_ + h) * DV_ + dv) * L_ + l0 + ch * 8] = o;
  }
}

// ---------------------------------------------------------------- flash attention v6 (r10-verified, unchanged)
__global__ __launch_bounds__(256, 2) void attn_kernel(const short* __restrict__ Hq,
                                                      const short* __restrict__ Hk,
                                                      const short* __restrict__ Hvt,
                                                      short* __restrict__ Aout) {
  __shared__ __align__(16) short lds[34816];
  const int tid = threadIdx.x;  // 0..255
  const int w = tid >> 6, lane = tid & 63;
  const int c31 = lane & 31, g1 = lane >> 5;
  const int sw = (blockIdx.x & 7) * 64 + (blockIdx.x >> 3);  // XCD swizzle (512 = 8*64)
  const int qb = sw & 7;
  const int h = (sw >> 3) & 15;
  const int b = sw >> 7;
  const int q0 = qb * 256;

  bf16x8 qf0[4], qf1[4];
#pragma unroll
  for (int hh = 0; hh < 2; ++hh) {
    const short* qptr =
        Hq + (size_t)(b * L_ + q0 + w * 64 + hh * 32 + c31) * D_ + h * 64 + g1 * 8;
#pragma unroll
    for (int ks = 0; ks < 4; ++ks) {
      bf16x8 raw = *(const bf16x8*)(qptr + ks * 16);
      u32x4 pk;
#pragma unroll
      for (int i = 0; i < 4; ++i)
        pk[i] = cvtpk(b2f(raw[2 * i]) * SCALE_LOG2, b2f(raw[2 * i + 1]) * SCALE_LOG2);
      if (hh == 0) qf0[ks] = __builtin_bit_cast(bf16x8, pk);
      else         qf1[ks] = __builtin_bit_cast(bf16x8, pk);
    }
  }

  f32x16 O00 = {}, O01 = {}, O10 = {}, O11 = {};
  float ls0 = 0.f, ls1 = 0.f;
  unsigned* Pw0 = (unsigned*)(lds + 16384) + (w * 2 + 0) * 1152;  // [32 q][36 u32]
  unsigned* Pw1 = (unsigned*)(lds + 16384) + (w * 2 + 1) * 1152;

  auto stage = [&](int buf, int kv0) {
    short* Kb = lds + buf * 8192;
    short* Vb = Kb + 4096;
#pragma unroll
    for (int it = 0; it < 2; ++it) {
      int slot = it * 256 + tid;
      int row = slot >> 3;
      int ch = (slot & 7) ^ (row & 7);  // pre-swizzled source chunk (rule #21)
      gl_lds16(Hk + (size_t)(b * L_ + kv0 + row) * D_ + h * 64 + ch * 8,
               Kb + (it * 256 + w * 64) * 8);
      gl_lds16(Hvt + (size_t)((b * H_ + h) * DV_ + row) * L_ + kv0 + ch * 8,
               Vb + (it * 256 + w * 64) * 8);
    }
  };

  stage(0, 0);
  int cur = 0;
  for (int t = 0; t < L_ / 64; ++t) {
    __syncthreads();  // vmcnt drained: buf[cur] ready
    if (t + 1 < L_ / 64) stage(cur ^ 1, (t + 1) * 64);  // prefetch under compute
    const short* Kb = lds + cur * 8192;
    const short* Vb = Kb + 4096;

    f32x16 sA0 = {}, sB0 = {}, sA1 = {}, sB1 = {};
    __builtin_amdgcn_s_setprio(1);
#pragma unroll
    for (int ks = 0; ks < 4; ++ks) {
      int cp = (((2 * ks + g1) ^ (c31 & 7)) * 8);
      bf16x8 k0 = *(const bf16x8*)(Kb + c31 * 64 + cp);
      bf16x8 k1 = *(const bf16x8*)(Kb + (32 + c31) * 64 + cp);
      sA0 = MFMA32(k0, qf0[ks], sA0);
      sB0 = MFMA32(k1, qf0[ks], sB0);
      sA1 = MFMA32(k0, qf1[ks], sA1);
      sB1 = MFMA32(k1, qf1[ks], sB1);
    }
    __builtin_amdgcn_s_setprio(0);

    {
      float rs = 0.f;
#pragma unroll
      for (int p = 0; p < 4; ++p) {
        float a0 = __builtin_amdgcn_exp2f(sA0[4 * p]);
        float a1 = __builtin_amdgcn_exp2f(sA0[4 * p + 1]);
        float a2 = __builtin_amdgcn_exp2f(sA0[4 * p + 2]);
        float a3 = __builtin_amdgcn_exp2f(sA0[4 * p + 3]);
        float b0 = __builtin_amdgcn_exp2f(sB0[4 * p]);
        float b1 = __builtin_amdgcn_exp2f(sB0[4 * p + 1]);
        float b2 = __builtin_amdgcn_exp2f(sB0[4 * p + 2]);
        float b3 = __builtin_amdgcn_exp2f(sB0[4 * p + 3]);
        rs += (a0 + a1) + (a2 + a3) + (b0 + b1) + (b2 + b3);
        u32x2 lo, hi;
        lo[0] = cvtpk(a0, a1);
        lo[1] = cvtpk(a2, a3);
        hi[0] = cvtpk(b0, b1);
        hi[1] = cvtpk(b2, b3);
        *(u32x2*)(Pw0 + c31 * 36 + 4 * p + 2 * g1) = lo;
        *(u32x2*)(Pw0 + c31 * 36 + 16 + 4 * p + 2 * g1) = hi;
      }
      ls0 += rs + __shfl_xor(rs, 32);
    }
    {
      float rs = 0.f;
#pragma unroll
      for (int p = 0; p < 4; ++p) {
        float a0 = __builtin_amdgcn_exp2f(sA1[4 * p]);
        float a1 = __builtin_amdgcn_exp2f(sA1[4 * p + 1]);
        float a2 = __builtin_amdgcn_exp2f(sA1[4 * p + 2]);
        float a3 = __builtin_amdgcn_exp2f(sA1[4 * p + 3]);
        float b0 = __builtin_amdgcn_exp2f(sB1[4 * p]);
        float b1 = __builtin_amdgcn_exp2f(sB1[4 * p + 1]);
        float b2 = __builtin_amdgcn_exp2f(sB1[4 * p + 2]);
        float b3 = __builtin_amdgcn_exp2f(sB1[4 * p + 3]);
        rs += (a0 + a1) + (a2 + a3) + (b0 + b1) + (b2 + b3);
        u32x2 lo, hi;
        lo[0] = cvtpk(a0, a1);
        lo[1] = cvtpk(a2, a3);
        hi[0] = cvtpk(b0, b1);
        hi[1] = cvtpk(b2, b3);
        *(u32x2*)(Pw1 + c31 * 36 + 4 * p + 2 * g1) = lo;
        *(u32x2*)(Pw1 + c31 * 36 + 16 + 4 * p + 2 * g1) = hi;
      }
      ls1 += rs + __shfl_xor(rs, 32);
    }

    __builtin_amdgcn_s_setprio(1);
#pragma unroll
    for (int ks2 = 0; ks2 < 4; ++ks2) {
      int cp = (((2 * ks2 + g1) ^ (c31 & 7)) * 8);
      bf16x8 vf0 = *(const bf16x8*)(Vb + c31 * 64 + cp);
      bf16x8 vf1 = *(const bf16x8*)(Vb + (32 + c31) * 64 + cp);
      u32x4 pk0 = *(const u32x4*)(Pw0 + c31 * 36 + ks2 * 8 + g1 * 4);
      bf16x8 pf0 = __builtin_bit_cast(bf16x8, pk0);
      O00 = MFMA32(vf0, pf0, O00);
      O01 = MFMA32(vf1, pf0, O01);
      u32x4 pk1 = *(const u32x4*)(Pw1 + c31 * 36 + ks2 * 8 + g1 * 4);
      bf16x8 pf1 = __builtin_bit_cast(bf16x8, pk1);
      O10 = MFMA32(vf0, pf1, O10);
      O11 = MFMA32(vf1, pf1, O11);
    }
    __builtin_amdgcn_s_setprio(0);
    cur ^= 1;
  }

  float inv0 = 1.0f / ls0;
  float inv1 = 1.0f / ls1;
  __syncthreads();
  short* Os = lds;
#define EPI(OA, OB, INV, HH)                                        \
  {                                                                 \
    _Pragma("unroll") for (int dt = 0; dt < 2; ++dt) {              \
      _Pragma("unroll") for (int rq = 0; rq < 4; ++rq) {            \
        float e0 = (dt ? OB[4 * rq] : OA[4 * rq]) * INV;            \
        float e1 = (dt ? OB[4 * rq + 1] : OA[4 * rq + 1]) * INV;    \
        float e2 = (dt ? OB[4 * rq + 2] : OA[4 * rq + 2]) * INV;    \
        float e3 = (dt ? OB[4 * rq + 3] : OA[4 * rq + 3]) * INV;    \
        u32x2 pr;                                                   \
        pr[0] = cvtpk(e0, e1);                                      \
        pr[1] = cvtpk(e2, e3);                                      \
        int q = w * 64 + (HH)*32 + c31;                             \
        int dv = dt * 32 + 8 * rq + 4 * g1;                         \
        *(u32x2*)&Os[q * 72 + dv] = pr;                             \
      }                                                             \
    }                                                               \
  }
  EPI(O00, O01, inv0, 0)
  EPI(O10, O11, inv1, 1)
#undef EPI
  __syncthreads();
#pragma unroll
  for (int it = 0; it < 2; ++it) {
    const int r = it * 128 + (tid >> 1), hf = tid & 1;
    const size_t obase = (size_t)(b * L_ + q0 + r) * D_ + h * 64 + hf * 32;
#pragma unroll
    for (int cc = 0; cc < 4; ++cc) {
      bf16x8 vv = *(const bf16x8*)&Os[r * 72 + hf * 32 + cc * 8];
      *(bf16x8*)&Aout[obase + cc * 8] = vv;
    }
  }
}

// ---------------------------------------------------------------- host
extern "C" void kernel_launch(void* const* d_in, const int* in_sizes, int n_in,
                              void* d_out, int out_size, void* d_ws, size_t ws_size,
                              hipStream_t stream) {
  (void)in_sizes; (void)n_in; (void)out_size; (void)ws_size;
  const float* q = (const float*)d_in[0];
  const float* k = (const float*)d_in[1];
  const float* v = (const float*)d_in[2];
  const float* Wq = (const float*)d_in[3];
  const float* bq = (const float*)d_in[4];
  const float* Wk = (const float*)d_in[5];
  const float* bk = (const float*)d_in[6];
  const float* Wv = (const float*)d_in[7];
  const float* bv = (const float*)d_in[8];
  const float* Wc = (const float*)d_in[9];
  const float* bc = (const float*)d_in[10];
  float* out = (float*)d_out;

  short* ws = (short*)d_ws;
  const size_t SZ = (size_t)M_ * D_;   // 8388608
  const size_t WSZ = (size_t)D_ * D_;  // 1048576
  short* wqb = ws;                      // 4 contiguous weight slots (wq,wk,wv,wc)
  short* wcb = ws + 3 * WSZ;
  short* hq = ws + 4 * WSZ;
  short* hk = hq + SZ;
  short* hv = hk + SZ;
  short* hvt = hv + SZ;
  short* aout = hv;  // hv slot free after transpose

  // all weights -> bf16 (one dispatch)
  dim3 gw(128, 4);
  cvtw_kernel<<<gw, 256, 0, stream>>>(Wq, Wk, Wv, Wc, wqb);

  // fused QKV projections: 128x256 tile, A staged once per K-step (2-panel reuse)
  dim3 gq(256, 3);
  gemm_qkvf<<<gq, 256, 0, stream>>>(q, k, v, wqb, bq, bk, bv, hq, hk, hv);

  // V transpose for attention A-operand
  transpose_kernel<<<2048, 256, 0, stream>>>(hv, hvt);

  // attention (512 blocks x 256 threads, 4 waves x 64 q, 2 blocks/CU)
  attn_kernel<<<512, 256, 0, stream>>>(hq, hk, hvt, aout);

  // output projection (f32 out + bias)
  gemm_bt<1><<<512, 256, 0, stream>>>(aout, wcb, bc, out, nullptr);
}

// Round 16
// 203.593 us; speedup vs baseline: 1.3883x; 1.2461x over previous
//
#include <hip/hip_runtime.h>

#define DI __device__ __forceinline__

typedef __attribute__((ext_vector_type(8))) short bf16x8;
typedef __attribute__((ext_vector_type(4))) float f32x4;
typedef __attribute__((ext_vector_type(16))) float f32x16;
typedef __attribute__((ext_vector_type(4))) unsigned u32x4;
typedef __attribute__((ext_vector_type(2))) unsigned u32x2;

static constexpr int B_ = 4, L_ = 2048, D_ = 1024, H_ = 16, DV_ = 64;
static constexpr int M_ = B_ * L_;  // 8192
static constexpr float SCALE_LOG2 = 0.18033688011112042f;  // (1/sqrt(64)) * log2(e)

DI short f2b(float f) {
  union { float f; unsigned u; } v; v.f = f;
  unsigned r = v.u + 0x7FFFu + ((v.u >> 16) & 1u);
  return (short)(r >> 16);
}

DI float b2f(short s) {
  union { unsigned u; float f; } v;
  v.u = ((unsigned)(unsigned short)s) << 16;
  return v.f;
}

DI unsigned cvtpk(float lo, float hi) {  // u32 = [bf16(lo) | bf16(hi)<<16]
  unsigned r;
  asm("v_cvt_pk_bf16_f32 %0, %1, %2" : "=v"(r) : "v"(lo), "v"(hi));
  return r;
}

DI void gl_lds16(const void* g, void* l) {
  __builtin_amdgcn_global_load_lds(
      (const __attribute__((address_space(1))) unsigned int*)g,
      (__attribute__((address_space(3))) unsigned int*)l, 16, 0, 0);
}

#define MFMA16(a, b, c) __builtin_amdgcn_mfma_f32_16x16x32_bf16((a), (b), (c), 0, 0, 0)
#define MFMA32(a, b, c) __builtin_amdgcn_mfma_f32_32x32x16_bf16((a), (b), (c), 0, 0, 0)

// ---------------------------------------------------------------- weights f32 -> bf16 (one dispatch, blockIdx.y selects)
__global__ __launch_bounds__(256) void cvtw_kernel(const float* __restrict__ W0,
                                                   const float* __restrict__ W1,
                                                   const float* __restrict__ W2,
                                                   const float* __restrict__ W3,
                                                   short* __restrict__ dst) {
  const int p = blockIdx.y;
  const float* s = p == 0 ? W0 : p == 1 ? W1 : p == 2 ? W2 : W3;
  short* d = dst + (size_t)p * 1048576;
  int i0 = (blockIdx.x * 256 + threadIdx.x) * 8;
  int stride = gridDim.x * 256 * 8;
  for (int i = i0; i < 1048576; i += stride) {
    float4 a = *(const float4*)(s + i);
    float4 b = *(const float4*)(s + i + 4);
    u32x4 o;
    o[0] = cvtpk(a.x, a.y);
    o[1] = cvtpk(a.z, a.w);
    o[2] = cvtpk(b.x, b.y);
    o[3] = cvtpk(b.z, b.w);
    *(u32x4*)(d + i) = o;
  }
}

// ---------------------------------------------------------------- fused QKV projection GEMM (f32 A, LDS-staged) — r10-verified
__global__ __launch_bounds__(256) void gemm_qkvf(const float* __restrict__ Xq,
                                                 const float* __restrict__ Xk,
                                                 const float* __restrict__ Xv,
                                                 const short* __restrict__ Wall,
                                                 const float* __restrict__ bq,
                                                 const float* __restrict__ bk,
                                                 const float* __restrict__ bv,
                                                 short* __restrict__ Hq,
                                                 short* __restrict__ Hk,
                                                 short* __restrict__ Hv) {
  constexpr int K = 1024, N = 1024;
  __shared__ __align__(16) float Asf[128 * 32];
  __shared__ __align__(16) short Bs[128 * 32];
  const int p = blockIdx.y;
  const float* A = p == 0 ? Xq : p == 1 ? Xk : Xv;
  const short* Wt = Wall + (size_t)p * 1048576;
  const float* bias = p == 0 ? bq : p == 1 ? bk : bv;
  short* outb = p == 0 ? Hq : p == 1 ? Hk : Hv;

  const int tid = threadIdx.x;
  const int w = tid >> 6, lane = tid & 63;
  const int c = lane & 15, g = lane >> 4;
  const int bid = (blockIdx.x & 7) * 64 + (blockIdx.x >> 3);  // XCD swizzle (512 = 8*64)
  const int bn = bid & 7, bm = bid >> 3;
  const int wr = w >> 1, wc = w & 1;

  f32x4 acc[4][4] = {};

  for (int kt = 0; kt < K / 32; ++kt) {
    __syncthreads();
#pragma unroll
    for (int it = 0; it < 4; ++it) {
      int slot = it * 256 + tid;
      int row = slot >> 3, ch = (slot & 7) ^ (row & 7);
      gl_lds16(A + ((size_t)(bm * 128 + row) * K + kt * 32 + ch * 4),
               &Asf[(it * 256 + w * 64) * 4]);
    }
#pragma unroll
    for (int ia = 0; ia < 2; ++ia) {
      int slot = ia * 256 + tid;
      int row = slot >> 2, ch = slot & 3;
      gl_lds16(Wt + ((size_t)(bn * 128 + row) * K + kt * 32 + ch * 8),
               &Bs[(ia * 256 + w * 64) * 8]);
    }
    __syncthreads();
    bf16x8 af[4], bf[4];
#pragma unroll
    for (int mi = 0; mi < 4; ++mi) {
      int r = wr * 64 + mi * 16 + c;
      int c0 = (((2 * g) ^ (r & 7)) * 4);
      int c1 = (((2 * g + 1) ^ (r & 7)) * 4);
      float4 lo = *(const float4*)&Asf[r * 32 + c0];
      float4 hi = *(const float4*)&Asf[r * 32 + c1];
      u32x4 pk;
      pk[0] = cvtpk(lo.x, lo.y);
      pk[1] = cvtpk(lo.z, lo.w);
      pk[2] = cvtpk(hi.x, hi.y);
      pk[3] = cvtpk(hi.z, hi.w);
      af[mi] = __builtin_bit_cast(bf16x8, pk);
    }
#pragma unroll
    for (int ni = 0; ni < 4; ++ni)
      bf[ni] = *(const bf16x8*)&Bs[(wc * 64 + ni * 16 + c) * 32 + g * 8];
#pragma unroll
    for (int mi = 0; mi < 4; ++mi)
#pragma unroll
      for (int ni = 0; ni < 4; ++ni)
        acc[mi][ni] = MFMA16(af[mi], bf[ni], acc[mi][ni]);
  }

  float bvv[4];
#pragma unroll
  for (int ni = 0; ni < 4; ++ni) bvv[ni] = bias[bn * 128 + wc * 64 + ni * 16 + c];
#pragma unroll
  for (int mi = 0; mi < 4; ++mi)
#pragma unroll
    for (int ni = 0; ni < 4; ++ni)
#pragma unroll
      for (int j = 0; j < 4; ++j) {
        int row = bm * 128 + wr * 64 + mi * 16 + g * 4 + j;
        int col = bn * 128 + wc * 64 + ni * 16 + c;
        outb[(size_t)row * N + col] = f2b(acc[mi][ni][j] + bvv[ni]);
      }
}

// ---------------------------------------------------------------- GEMM (bf16 A): final projection (proven)
template <int OUTF32>
__global__ __launch_bounds__(256) void gemm_bt(const short* __restrict__ A,
                                               const short* __restrict__ Wt,
                                               const float* __restrict__ bias,
                                               float* __restrict__ outf,
                                               short* __restrict__ outb) {
  constexpr int K = 1024, N = 1024;
  __shared__ __align__(16) short As[128 * 32];
  __shared__ __align__(16) short Bs[128 * 32];
  const int tid = threadIdx.x;
  const int w = tid >> 6, lane = tid & 63;
  const int c = lane & 15, g = lane >> 4;
  const int bid = (blockIdx.x & 7) * 64 + (blockIdx.x >> 3);  // XCD swizzle (512 = 8*64)
  const int bn = bid & 7, bm = bid >> 3;
  const int wr = w >> 1, wc = w & 1;

  f32x4 acc[4][4] = {};

  for (int kt = 0; kt < K / 32; ++kt) {
    __syncthreads();
#pragma unroll
    for (int ia = 0; ia < 2; ++ia) {
      int slot = ia * 256 + tid;
      int row = slot >> 2, ch = slot & 3;
      gl_lds16(A + ((size_t)(bm * 128 + row) * K + kt * 32 + ch * 8),
               &As[(ia * 256 + w * 64) * 8]);
      gl_lds16(Wt + ((size_t)(bn * 128 + row) * K + kt * 32 + ch * 8),
               &Bs[(ia * 256 + w * 64) * 8]);
    }
    __syncthreads();
    bf16x8 af[4], bf[4];
#pragma unroll
    for (int mi = 0; mi < 4; ++mi)
      af[mi] = *(const bf16x8*)&As[(wr * 64 + mi * 16 + c) * 32 + g * 8];
#pragma unroll
    for (int ni = 0; ni < 4; ++ni)
      bf[ni] = *(const bf16x8*)&Bs[(wc * 64 + ni * 16 + c) * 32 + g * 8];
#pragma unroll
    for (int mi = 0; mi < 4; ++mi)
#pragma unroll
      for (int ni = 0; ni < 4; ++ni)
        acc[mi][ni] = MFMA16(af[mi], bf[ni], acc[mi][ni]);
  }

  float bv[4];
#pragma unroll
  for (int ni = 0; ni < 4; ++ni) bv[ni] = bias[bn * 128 + wc * 64 + ni * 16 + c];
#pragma unroll
  for (int mi = 0; mi < 4; ++mi)
#pragma unroll
    for (int ni = 0; ni < 4; ++ni)
#pragma unroll
      for (int j = 0; j < 4; ++j) {
        int row = bm * 128 + wr * 64 + mi * 16 + g * 4 + j;
        int col = bn * 128 + wc * 64 + ni * 16 + c;
        float v = acc[mi][ni][j] + bv[ni];
        if (OUTF32)
          outf[(size_t)row * N + col] = v;
        else
          outb[(size_t)row * N + col] = f2b(v);
      }
}

// ---------------------------------------------------------------- Hv [B,L,D] -> Hvt [B,H,DV,L] (proven)
__global__ __launch_bounds__(256) void transpose_kernel(const short* __restrict__ Hv,
                                                        short* __restrict__ Hvt) {
  __shared__ short T[64 * 72];
  int bid = blockIdx.x;
  const int lt = bid & 31;
  const int h = (bid >> 5) & 15;
  const int b = bid >> 9;
  const int l0 = lt * 64;
  const int tid = threadIdx.x;
#pragma unroll
  for (int it = 0; it < 2; ++it) {
    int slot = it * 256 + tid;
    int r = slot >> 3, ch = slot & 7;
    bf16x8 v = *(const bf16x8*)&Hv[(size_t)(b * L_ + l0 + r) * D_ + h * DV_ + ch * 8];
    *(bf16x8*)&T[r * 72 + ch * 8] = v;
  }
  __syncthreads();
#pragma unroll
  for (int it = 0; it < 2; ++it) {
    int slot = it * 256 + tid;
    int dv = slot >> 3, ch = slot & 7;
    bf16x8 o;
#pragma unroll
    for (int i = 0; i < 8; ++i) o[i] = T[(ch * 8 + i) * 72 + dv];
    *(bf16x8*)&Hvt[(size_t)((b * H_ + h) * DV_ + dv) * L_ + l0 + ch * 8] = o;
  }
}

// ---------------------------------------------------------------- flash attention v6 (r10-verified: 4 waves x 64 q,
// LDS-P carrier in [q][kv_u32] stride-36 layout, swizzled K/V, swapped QK^T, 2 blocks/CU)
__global__ __launch_bounds__(256, 2) void attn_kernel(const short* __restrict__ Hq,
                                                      const short* __restrict__ Hk,
                                                      const short* __restrict__ Hvt,
                                                      short* __restrict__ Aout) {
  __shared__ __align__(16) short lds[34816];
  const int tid = threadIdx.x;  // 0..255
  const int w = tid >> 6, lane = tid & 63;
  const int c31 = lane & 31, g1 = lane >> 5;
  const int sw = (blockIdx.x & 7) * 64 + (blockIdx.x >> 3);  // XCD swizzle (512 = 8*64)
  const int qb = sw & 7;
  const int h = (sw >> 3) & 15;
  const int b = sw >> 7;
  const int q0 = qb * 256;

  bf16x8 qf0[4], qf1[4];
#pragma unroll
  for (int hh = 0; hh < 2; ++hh) {
    const short* qptr =
        Hq + (size_t)(b * L_ + q0 + w * 64 + hh * 32 + c31) * D_ + h * 64 + g1 * 8;
#pragma unroll
    for (int ks = 0; ks < 4; ++ks) {
      bf16x8 raw = *(const bf16x8*)(qptr + ks * 16);
      u32x4 pk;
#pragma unroll
      for (int i = 0; i < 4; ++i)
        pk[i] = cvtpk(b2f(raw[2 * i]) * SCALE_LOG2, b2f(raw[2 * i + 1]) * SCALE_LOG2);
      if (hh == 0) qf0[ks] = __builtin_bit_cast(bf16x8, pk);
      else         qf1[ks] = __builtin_bit_cast(bf16x8, pk);
    }
  }

  f32x16 O00 = {}, O01 = {}, O10 = {}, O11 = {};
  float ls0 = 0.f, ls1 = 0.f;
  unsigned* Pw0 = (unsigned*)(lds + 16384) + (w * 2 + 0) * 1152;  // [32 q][36 u32]
  unsigned* Pw1 = (unsigned*)(lds + 16384) + (w * 2 + 1) * 1152;

  auto stage = [&](int buf, int kv0) {
    short* Kb = lds + buf * 8192;
    short* Vb = Kb + 4096;
#pragma unroll
    for (int it = 0; it < 2; ++it) {
      int slot = it * 256 + tid;
      int row = slot >> 3;
      int ch = (slot & 7) ^ (row & 7);  // pre-swizzled source chunk (rule #21)
      gl_lds16(Hk + (size_t)(b * L_ + kv0 + row) * D_ + h * 64 + ch * 8,
               Kb + (it * 256 + w * 64) * 8);
      gl_lds16(Hvt + (size_t)((b * H_ + h) * DV_ + row) * L_ + kv0 + ch * 8,
               Vb + (it * 256 + w * 64) * 8);
    }
  };

  stage(0, 0);
  int cur = 0;
  for (int t = 0; t < L_ / 64; ++t) {
    __syncthreads();  // vmcnt drained: buf[cur] ready
    if (t + 1 < L_ / 64) stage(cur ^ 1, (t + 1) * 64);  // prefetch under compute
    const short* Kb = lds + cur * 8192;
    const short* Vb = Kb + 4096;

    f32x16 sA0 = {}, sB0 = {}, sA1 = {}, sB1 = {};
    __builtin_amdgcn_s_setprio(1);
#pragma unroll
    for (int ks = 0; ks < 4; ++ks) {
      int cp = (((2 * ks + g1) ^ (c31 & 7)) * 8);
      bf16x8 k0 = *(const bf16x8*)(Kb + c31 * 64 + cp);
      bf16x8 k1 = *(const bf16x8*)(Kb + (32 + c31) * 64 + cp);
      sA0 = MFMA32(k0, qf0[ks], sA0);
      sB0 = MFMA32(k1, qf0[ks], sB0);
      sA1 = MFMA32(k0, qf1[ks], sA1);
      sB1 = MFMA32(k1, qf1[ks], sB1);
    }
    __builtin_amdgcn_s_setprio(0);

    {
      float rs = 0.f;
#pragma unroll
      for (int p = 0; p < 4; ++p) {
        float a0 = __builtin_amdgcn_exp2f(sA0[4 * p]);
        float a1 = __builtin_amdgcn_exp2f(sA0[4 * p + 1]);
        float a2 = __builtin_amdgcn_exp2f(sA0[4 * p + 2]);
        float a3 = __builtin_amdgcn_exp2f(sA0[4 * p + 3]);
        float b0 = __builtin_amdgcn_exp2f(sB0[4 * p]);
        float b1 = __builtin_amdgcn_exp2f(sB0[4 * p + 1]);
        float b2 = __builtin_amdgcn_exp2f(sB0[4 * p + 2]);
        float b3 = __builtin_amdgcn_exp2f(sB0[4 * p + 3]);
        rs += (a0 + a1) + (a2 + a3) + (b0 + b1) + (b2 + b3);
        u32x2 lo, hi;
        lo[0] = cvtpk(a0, a1);
        lo[1] = cvtpk(a2, a3);
        hi[0] = cvtpk(b0, b1);
        hi[1] = cvtpk(b2, b3);
        *(u32x2*)(Pw0 + c31 * 36 + 4 * p + 2 * g1) = lo;
        *(u32x2*)(Pw0 + c31 * 36 + 16 + 4 * p + 2 * g1) = hi;
      }
      ls0 += rs + __shfl_xor(rs, 32);
    }
    {
      float rs = 0.f;
#pragma unroll
      for (int p = 0; p < 4; ++p) {
        float a0 = __builtin_amdgcn_exp2f(sA1[4 * p]);
        float a1 = __builtin_amdgcn_exp2f(sA1[4 * p + 1]);
        float a2 = __builtin_amdgcn_exp2f(sA1[4 * p + 2]);
        float a3 = __builtin_amdgcn_exp2f(sA1[4 * p + 3]);
        float b0 = __builtin_amdgcn_exp2f(sB1[4 * p]);
        float b1 = __builtin_amdgcn_exp2f(sB1[4 * p + 1]);
        float b2 = __builtin_amdgcn_exp2f(sB1[4 * p + 2]);
        float b3 = __builtin_amdgcn_exp2f(sB1[4 * p + 3]);
        rs += (a0 + a1) + (a2 + a3) + (b0 + b1) + (b2 + b3);
        u32x2 lo, hi;
        lo[0] = cvtpk(a0, a1);
        lo[1] = cvtpk(a2, a3);
        hi[0] = cvtpk(b0, b1);
        hi[1] = cvtpk(b2, b3);
        *(u32x2*)(Pw1 + c31 * 36 + 4 * p + 2 * g1) = lo;
        *(u32x2*)(Pw1 + c31 * 36 + 16 + 4 * p + 2 * g1) = hi;
      }
      ls1 += rs + __shfl_xor(rs, 32);
    }

    __builtin_amdgcn_s_setprio(1);
#pragma unroll
    for (int ks2 = 0; ks2 < 4; ++ks2) {
      int cp = (((2 * ks2 + g1) ^ (c31 & 7)) * 8);
      bf16x8 vf0 = *(const bf16x8*)(Vb + c31 * 64 + cp);
      bf16x8 vf1 = *(const bf16x8*)(Vb + (32 + c31) * 64 + cp);
      u32x4 pk0 = *(const u32x4*)(Pw0 + c31 * 36 + ks2 * 8 + g1 * 4);
      bf16x8 pf0 = __builtin_bit_cast(bf16x8, pk0);
      O00 = MFMA32(vf0, pf0, O00);
      O01 = MFMA32(vf1, pf0, O01);
      u32x4 pk1 = *(const u32x4*)(Pw1 + c31 * 36 + ks2 * 8 + g1 * 4);
      bf16x8 pf1 = __builtin_bit_cast(bf16x8, pk1);
      O10 = MFMA32(vf0, pf1, O10);
      O11 = MFMA32(vf1, pf1, O11);
    }
    __builtin_amdgcn_s_setprio(0);
    cur ^= 1;
  }

  float inv0 = 1.0f / ls0;
  float inv1 = 1.0f / ls1;
  __syncthreads();
  short* Os = lds;
#define EPI(OA, OB, INV, HH)                                        \
  {                                                                 \
    _Pragma("unroll") for (int dt = 0; dt < 2; ++dt) {              \
      _Pragma("unroll") for (int rq = 0; rq < 4; ++rq) {            \
        float e0 = (dt ? OB[4 * rq] : OA[4 * rq]) * INV;            \
        float e1 = (dt ? OB[4 * rq + 1] : OA[4 * rq + 1]) * INV;    \
        float e2 = (dt ? OB[4 * rq + 2] : OA[4 * rq + 2]) * INV;    \
        float e3 = (dt ? OB[4 * rq + 3] : OA[4 * rq + 3]) * INV;    \
        u32x2 pr;                                                   \
        pr[0] = cvtpk(e0, e1);                                      \
        pr[1] = cvtpk(e2, e3);                                      \
        int q = w * 64 + (HH)*32 + c31;                             \
        int dv = dt * 32 + 8 * rq + 4 * g1;                         \
        *(u32x2*)&Os[q * 72 + dv] = pr;                             \
      }                                                             \
    }                                                               \
  }
  EPI(O00, O01, inv0, 0)
  EPI(O10, O11, inv1, 1)
#undef EPI
  __syncthreads();
#pragma unroll
  for (int it = 0; it < 2; ++it) {
    const int r = it * 128 + (tid >> 1), hf = tid & 1;
    const size_t obase = (size_t)(b * L_ + q0 + r) * D_ + h * 64 + hf * 32;
#pragma unroll
    for (int cc = 0; cc < 4; ++cc) {
      bf16x8 vv = *(const bf16x8*)&Os[r * 72 + hf * 32 + cc * 8];
      *(bf16x8*)&Aout[obase + cc * 8] = vv;
    }
  }
}

// ---------------------------------------------------------------- host
extern "C" void kernel_launch(void* const* d_in, const int* in_sizes, int n_in,
                              void* d_out, int out_size, void* d_ws, size_t ws_size,
                              hipStream_t stream) {
  (void)in_sizes; (void)n_in; (void)out_size; (void)ws_size;
  const float* q = (const float*)d_in[0];
  const float* k = (const float*)d_in[1];
  const float* v = (const float*)d_in[2];
  const float* Wq = (const float*)d_in[3];
  const float* bq = (const float*)d_in[4];
  const float* Wk = (const float*)d_in[5];
  const float* bk = (const float*)d_in[6];
  const float* Wv = (const float*)d_in[7];
  const float* bv = (const float*)d_in[8];
  const float* Wc = (const float*)d_in[9];
  const float* bc = (const float*)d_in[10];
  float* out = (float*)d_out;

  short* ws = (short*)d_ws;
  const size_t SZ = (size_t)M_ * D_;   // 8388608
  const size_t WSZ = (size_t)D_ * D_;  // 1048576
  short* wqb = ws;                      // 4 contiguous weight slots (wq,wk,wv,wc)
  short* wcb = ws + 3 * WSZ;
  short* hq = ws + 4 * WSZ;
  short* hk = hq + SZ;
  short* hv = hk + SZ;
  short* hvt = hv + SZ;
  short* aout = hv;  // hv slot free after transpose

  // all weights -> bf16 (one dispatch)
  dim3 gw(128, 4);
  cvtw_kernel<<<gw, 256, 0, stream>>>(Wq, Wk, Wv, Wc, wqb);

  // fused QKV projections (f32 A staged to LDS, in-register cvt) — r10-verified
  dim3 gq(512, 3);
  gemm_qkvf<<<gq, 256, 0, stream>>>(q, k, v, wqb, bq, bk, bv, hq, hk, hv);

  // V transpose for attention A-operand
  transpose_kernel<<<2048, 256, 0, stream>>>(hv, hvt);

  // attention (512 blocks x 256 threads, 4 waves x 64 q, 2 blocks/CU)
  attn_kernel<<<512, 256, 0, stream>>>(hq, hk, hvt, aout);

  // output projection (f32 out + bias)
  gemm_bt<1><<<512, 256, 0, stream>>>(aout, wcb, bc, out, nullptr);
}